// Round 1
// baseline (821.776 us; speedup 1.0000x reference)
//
#include <hip/hip_runtime.h>
#include <hip/hip_bf16.h>

#define NN 100000
#define NE 1600000
#define DD 64

constexpr float LAM = 2.0f;
constexpr float C1A = -2.0f / LAM;        // -1
constexpr float C1B = 2.0f / LAM - 1.0f;  //  0
constexpr float C2A = -4.0f / LAM;        // -2
constexpr float C2B = 4.0f / LAM - 2.0f;  //  0

typedef __attribute__((ext_vector_type(4))) float f32x4;
typedef __attribute__((ext_vector_type(8))) short bf16x8;

__device__ __forceinline__ short f2bf(float x) {
    __hip_bfloat16 h = __float2bfloat16(x);
    return __builtin_bit_cast(short, h);
}

__global__ void deg_kernel(const int* __restrict__ dst, float* __restrict__ deg, int E) {
    int e = blockIdx.x * blockDim.x + threadIdx.x;
    if (e < E) unsafeAtomicAdd(&deg[dst[e]], 1.0f);
}

__global__ void norm_kernel(float* __restrict__ deg, int N) {
    int i = blockIdx.x * blockDim.x + threadIdx.x;
    if (i < N) deg[i] = rsqrtf(fmaxf(deg[i], 1.0f));
}

// PASS 0: out[dst] += feat[src] * norm[src]
// PASS 1: out[dst] += t1raw[src] * (C1A*norm[src]^2)  [+ C1B*norm[src]*feat[src], folded out]
template <int PASS>
__global__ void scatter_kernel(const float* __restrict__ x,
                               const float* __restrict__ feat,
                               const float* __restrict__ norm,
                               const int* __restrict__ src,
                               const int* __restrict__ dst,
                               float* __restrict__ out, int E) {
    int e = blockIdx.x * 4 + (threadIdx.x >> 6);  // one 64-lane wave per edge
    int lane = threadIdx.x & 63;
    if (e >= E) return;
    int s = src[e];
    int t = dst[e];
    float ns = norm[s];
    float v;
    if (PASS == 0) {
        v = x[(size_t)s * DD + lane] * ns;
    } else {
        v = x[(size_t)s * DD + lane] * (C1A * ns * ns);
        if (C1B != 0.0f) v += feat[(size_t)s * DD + lane] * (C1B * ns);
    }
    unsafeAtomicAdd(&out[(size_t)t * DD + lane], v);
}

// out = feat@W0 + Tx1@W1 + Tx2@W2 + bias, Tx computed on the fly from raw sums.
__launch_bounds__(256)
__global__ void out_kernel(const float* __restrict__ feat,
                           const float* __restrict__ t1raw,
                           const float* __restrict__ t2raw,
                           const float* __restrict__ norm,
                           const float* __restrict__ W,
                           const float* __restrict__ bias,
                           float* __restrict__ out, int N) {
    // W transposed to [mat][n][k] in bf16, rows padded 64->72 (144B stride -> 2-way banks, free)
    __shared__ __align__(16) short sW[3][64][72];
    for (int idx = threadIdx.x; idx < 3 * 64 * 64; idx += 256) {
        int m = idx >> 12;
        int r = idx & 4095;
        int k = r >> 6;
        int n = r & 63;
        sW[m][n][k] = f2bf(W[idx]);  // W flat = m*4096 + k*64 + n
    }
    __syncthreads();

    int wave = threadIdx.x >> 6;
    int lane = threadIdx.x & 63;
    int rowtile = blockIdx.x * 64 + wave * 16;
    if (rowtile >= N) return;
    int lrow = lane & 15;
    int lk = (lane >> 4) << 3;  // 0,8,16,24
    int row = rowtile + lrow;
    bool rv = row < N;
    float nrm = rv ? norm[row] : 0.0f;

    // A fragments for [X0 | Tx1 | Tx2], 2 K-steps of 32 each
    bf16x8 a[3][2];
    for (int s = 0; s < 2; ++s) {
        float xf[8], x1[8], x2[8];
        if (rv) {
            size_t base = (size_t)row * DD + s * 32 + lk;
            f32x4 fa = *(const f32x4*)(feat + base);
            f32x4 fb = *(const f32x4*)(feat + base + 4);
            f32x4 ta = *(const f32x4*)(t1raw + base);
            f32x4 tb = *(const f32x4*)(t1raw + base + 4);
            f32x4 ua = *(const f32x4*)(t2raw + base);
            f32x4 ub = *(const f32x4*)(t2raw + base + 4);
            for (int j = 0; j < 4; ++j) {
                xf[j] = fa[j]; xf[4 + j] = fb[j];
                x1[j] = ta[j]; x1[4 + j] = tb[j];
                x2[j] = ua[j]; x2[4 + j] = ub[j];
            }
        } else {
            for (int j = 0; j < 8; ++j) { xf[j] = 0.f; x1[j] = 0.f; x2[j] = 0.f; }
        }
        for (int j = 0; j < 8; ++j) {
            float T1 = C1A * nrm * x1[j] + C1B * xf[j];
            float T2 = C2A * nrm * x2[j] + C2B * T1 - xf[j];
            a[0][s][j] = f2bf(xf[j]);
            a[1][s][j] = f2bf(T1);
            a[2][s][j] = f2bf(T2);
        }
    }

    f32x4 acc[4];
    for (int ct = 0; ct < 4; ++ct) acc[ct] = (f32x4){0.f, 0.f, 0.f, 0.f};

    for (int m = 0; m < 3; ++m)
        for (int s = 0; s < 2; ++s)
            for (int ct = 0; ct < 4; ++ct) {
                bf16x8 b = *(const bf16x8*)&sW[m][ct * 16 + lrow][s * 32 + lk];
                acc[ct] = __builtin_amdgcn_mfma_f32_16x16x32_bf16(a[m][s], b, acc[ct], 0, 0, 0);
            }

    // C/D layout: col = lane&15, row = (lane>>4)*4 + reg  [verified m89/m91]
    int rbase = rowtile + ((lane >> 4) << 2);
    for (int ct = 0; ct < 4; ++ct) {
        int col = ct * 16 + lrow;
        float bv = bias[col];
        for (int r = 0; r < 4; ++r) {
            int ro = rbase + r;
            if (ro < N) out[(size_t)ro * DD + col] = acc[ct][r] + bv;
        }
    }
}

extern "C" void kernel_launch(void* const* d_in, const int* in_sizes, int n_in,
                              void* d_out, int out_size, void* d_ws, size_t ws_size,
                              hipStream_t stream) {
    const float* feat = (const float*)d_in[0];
    const float* W    = (const float*)d_in[1];
    const float* bias = (const float*)d_in[2];
    const int* esrc   = (const int*)d_in[3];
    const int* edst   = (const int*)d_in[4];
    float* out = (float*)d_out;

    char* ws = (char*)d_ws;
    float* norm = (float*)ws;  // NN floats (deg then norm, in place)
    size_t o1 = ((size_t)NN * 4 + 255) & ~(size_t)255;
    float* t1 = (float*)(ws + o1);
    float* t2 = (float*)(ws + o1 + (size_t)NN * DD * 4);

    // zero deg + both accumulation buffers (t1,t2 contiguous)
    hipMemsetAsync(norm, 0, (size_t)NN * 4, stream);
    hipMemsetAsync(t1, 0, (size_t)2 * NN * DD * 4, stream);

    deg_kernel<<<(NE + 255) / 256, 256, 0, stream>>>(edst, norm, NE);
    norm_kernel<<<(NN + 255) / 256, 256, 0, stream>>>(norm, NN);
    scatter_kernel<0><<<(NE + 3) / 4, 256, 0, stream>>>(feat, feat, norm, esrc, edst, t1, NE);
    scatter_kernel<1><<<(NE + 3) / 4, 256, 0, stream>>>(t1, feat, norm, esrc, edst, t2, NE);
    out_kernel<<<(NN + 63) / 64, 256, 0, stream>>>(feat, t1, t2, norm, W, bias, out, NN);
}

// Round 2
// 704.253 us; speedup vs baseline: 1.1669x; 1.1669x over previous
//
#include <hip/hip_runtime.h>
#include <hip/hip_bf16.h>

#define NN 100000
#define NE 1600000
#define DD 64

constexpr float LAM = 2.0f;
constexpr float C1A = -2.0f / LAM;        // -1
constexpr float C1B = 2.0f / LAM - 1.0f;  //  0
constexpr float C2A = -4.0f / LAM;        // -2
constexpr float C2B = 4.0f / LAM - 2.0f;  //  0

typedef __attribute__((ext_vector_type(4))) float f32x4;
typedef __attribute__((ext_vector_type(8))) short bf16x8;

__device__ __forceinline__ short f2bf(float x) {
    __hip_bfloat16 h = __float2bfloat16(x);
    return __builtin_bit_cast(short, h);
}

__global__ void hist_kernel(const int* __restrict__ dst, int* __restrict__ cnt, int E) {
    int e = blockIdx.x * blockDim.x + threadIdx.x;
    if (e < E) atomicAdd(&cnt[dst[e]], 1);
}

// Single-block scan: cnt -> row_ptr (exclusive), cursor copy, norm = rsqrt(max(deg,1))
__launch_bounds__(1024)
__global__ void scan_kernel(const int* __restrict__ cnt, int* __restrict__ rowp,
                            int* __restrict__ cursor, float* __restrict__ norm, int N) {
    __shared__ int sums[1024];
    int t = threadIdx.x;
    int C = (N + 1023) / 1024;
    int lo = t * C;
    int hi = min(lo + C, N);
    int s = 0;
    for (int i = lo; i < hi; ++i) s += cnt[i];
    sums[t] = s;
    __syncthreads();
    for (int off = 1; off < 1024; off <<= 1) {
        int v = (t >= off) ? sums[t - off] : 0;
        __syncthreads();
        sums[t] += v;
        __syncthreads();
    }
    int run = sums[t] - s;  // exclusive prefix
    for (int i = lo; i < hi; ++i) {
        int c = cnt[i];
        rowp[i] = run;
        cursor[i] = run;
        norm[i] = rsqrtf(fmaxf((float)c, 1.0f));
        run += c;
    }
    if (t == 1023) rowp[N] = run;  // last chunk empty or ends at N -> run == total
}

__global__ void fill_kernel(const int* __restrict__ src, const int* __restrict__ dst,
                            int* __restrict__ cursor, int* __restrict__ col, int E) {
    int e = blockIdx.x * blockDim.x + threadIdx.x;
    if (e < E) {
        int d = dst[e];
        int pos = atomicAdd(&cursor[d], 1);
        col[pos] = src[e];
    }
}

// PASS 0: out[n] = sum_{e: dst=n} norm[s] * x[s]            (raw agg numerator for Tx1)
// PASS 1: out[n] = sum_{e: dst=n} (C1A*norm[s]^2) * x[s]    (+ C1B*norm[s]*feat[s], folds to 0)
template <int PASS>
__global__ void gather_kernel(const float* __restrict__ x,
                              const float* __restrict__ feat,
                              const float* __restrict__ norm,
                              const int* __restrict__ rowp,
                              const int* __restrict__ col,
                              float* __restrict__ out, int N) {
    int n = blockIdx.x * 4 + (threadIdx.x >> 6);
    int lane = threadIdx.x & 63;
    if (n >= N) return;
    int beg = rowp[n];
    int end = rowp[n + 1];
    float acc = 0.0f;
    float accf = 0.0f;
    for (int base = beg; base < end; base += 64) {
        int m = min(64, end - base);
        int idx = (lane < m) ? col[base + lane] : 0;
        float nw = (lane < m) ? norm[idx] : 0.0f;
        float w = (PASS == 1) ? (C1A * nw * nw) : nw;
#pragma unroll 4
        for (int t = 0; t < m; ++t) {
            int s = __shfl(idx, t);
            float ww = __shfl(w, t);
            acc += ww * x[(size_t)s * DD + lane];
            if (PASS == 1 && C1B != 0.0f) {
                float w2 = __shfl(nw, t);
                accf += w2 * feat[(size_t)s * DD + lane];
            }
        }
    }
    if (PASS == 1 && C1B != 0.0f) acc += C1B * accf;
    out[(size_t)n * DD + lane] = acc;
}

// out = feat@W0 + Tx1@W1 + Tx2@W2 + bias, Tx computed on the fly from raw sums.
__launch_bounds__(256)
__global__ void out_kernel(const float* __restrict__ feat,
                           const float* __restrict__ t1raw,
                           const float* __restrict__ t2raw,
                           const float* __restrict__ norm,
                           const float* __restrict__ W,
                           const float* __restrict__ bias,
                           float* __restrict__ out, int N) {
    // W transposed to [mat][n][k] in bf16, rows padded 64->72 (2-way banks, free)
    __shared__ __align__(16) short sW[3][64][72];
    for (int idx = threadIdx.x; idx < 3 * 64 * 64; idx += 256) {
        int m = idx >> 12;
        int r = idx & 4095;
        int k = r >> 6;
        int n = r & 63;
        sW[m][n][k] = f2bf(W[idx]);  // W flat = m*4096 + k*64 + n
    }
    __syncthreads();

    int wave = threadIdx.x >> 6;
    int lane = threadIdx.x & 63;
    int rowtile = blockIdx.x * 64 + wave * 16;
    if (rowtile >= N) return;
    int lrow = lane & 15;
    int lk = (lane >> 4) << 3;  // 0,8,16,24
    int row = rowtile + lrow;
    bool rv = row < N;
    float nrm = rv ? norm[row] : 0.0f;

    bf16x8 a[3][2];
    for (int s = 0; s < 2; ++s) {
        float xf[8], x1[8], x2[8];
        if (rv) {
            size_t base = (size_t)row * DD + s * 32 + lk;
            f32x4 fa = *(const f32x4*)(feat + base);
            f32x4 fb = *(const f32x4*)(feat + base + 4);
            f32x4 ta = *(const f32x4*)(t1raw + base);
            f32x4 tb = *(const f32x4*)(t1raw + base + 4);
            f32x4 ua = *(const f32x4*)(t2raw + base);
            f32x4 ub = *(const f32x4*)(t2raw + base + 4);
            for (int j = 0; j < 4; ++j) {
                xf[j] = fa[j]; xf[4 + j] = fb[j];
                x1[j] = ta[j]; x1[4 + j] = tb[j];
                x2[j] = ua[j]; x2[4 + j] = ub[j];
            }
        } else {
            for (int j = 0; j < 8; ++j) { xf[j] = 0.f; x1[j] = 0.f; x2[j] = 0.f; }
        }
        for (int j = 0; j < 8; ++j) {
            float T1 = C1A * nrm * x1[j] + C1B * xf[j];
            float T2 = C2A * nrm * x2[j] + C2B * T1 - xf[j];
            a[0][s][j] = f2bf(xf[j]);
            a[1][s][j] = f2bf(T1);
            a[2][s][j] = f2bf(T2);
        }
    }

    f32x4 acc[4];
    for (int ct = 0; ct < 4; ++ct) acc[ct] = (f32x4){0.f, 0.f, 0.f, 0.f};

    for (int m = 0; m < 3; ++m)
        for (int s = 0; s < 2; ++s)
            for (int ct = 0; ct < 4; ++ct) {
                bf16x8 b = *(const bf16x8*)&sW[m][ct * 16 + lrow][s * 32 + lk];
                acc[ct] = __builtin_amdgcn_mfma_f32_16x16x32_bf16(a[m][s], b, acc[ct], 0, 0, 0);
            }

    // C/D layout: col = lane&15, row = (lane>>4)*4 + reg  [verified m89/m91]
    int rbase = rowtile + ((lane >> 4) << 2);
    for (int ct = 0; ct < 4; ++ct) {
        int colo = ct * 16 + lrow;
        float bv = bias[colo];
        for (int r = 0; r < 4; ++r) {
            int ro = rbase + r;
            if (ro < N) out[(size_t)ro * DD + colo] = acc[ct][r] + bv;
        }
    }
}

extern "C" void kernel_launch(void* const* d_in, const int* in_sizes, int n_in,
                              void* d_out, int out_size, void* d_ws, size_t ws_size,
                              hipStream_t stream) {
    const float* feat = (const float*)d_in[0];
    const float* W    = (const float*)d_in[1];
    const float* bias = (const float*)d_in[2];
    const int* esrc   = (const int*)d_in[3];
    const int* edst   = (const int*)d_in[4];
    float* out = (float*)d_out;

    char* ws = (char*)d_ws;
    size_t off = 0;
    auto alloc = [&](size_t bytes) {
        void* p = ws + off;
        off = (off + bytes + 255) & ~(size_t)255;
        return p;
    };
    int*   cnt    = (int*)alloc((size_t)NN * 4);
    int*   rowp   = (int*)alloc(((size_t)NN + 1) * 4);
    int*   cursor = (int*)alloc((size_t)NN * 4);
    float* norm   = (float*)alloc((size_t)NN * 4);
    int*   col    = (int*)alloc((size_t)NE * 4);
    float* t1     = (float*)alloc((size_t)NN * DD * 4);
    float* t2     = (float*)alloc((size_t)NN * DD * 4);

    hipMemsetAsync(cnt, 0, (size_t)NN * 4, stream);

    hist_kernel<<<(NE + 255) / 256, 256, 0, stream>>>(edst, cnt, NE);
    scan_kernel<<<1, 1024, 0, stream>>>(cnt, rowp, cursor, norm, NN);
    fill_kernel<<<(NE + 255) / 256, 256, 0, stream>>>(esrc, edst, cursor, col, NE);
    gather_kernel<0><<<(NN + 3) / 4, 256, 0, stream>>>(feat, feat, norm, rowp, col, t1, NN);
    gather_kernel<1><<<(NN + 3) / 4, 256, 0, stream>>>(t1, feat, norm, rowp, col, t2, NN);
    out_kernel<<<(NN + 63) / 64, 256, 0, stream>>>(feat, t1, t2, norm, W, bias, out, NN);
}

// Round 3
// 421.833 us; speedup vs baseline: 1.9481x; 1.6695x over previous
//
#include <hip/hip_runtime.h>
#include <hip/hip_bf16.h>

#define NN 100000
#define NE 1600000
#define DD 64
#define CH 1024
#define NB ((NN + CH - 1) / CH)  // 98 blocks

constexpr float LAM = 2.0f;
constexpr float C1A = -2.0f / LAM;        // -1
constexpr float C1B = 2.0f / LAM - 1.0f;  //  0
constexpr float C2A = -4.0f / LAM;        // -2
constexpr float C2B = 4.0f / LAM - 2.0f;  //  0

typedef __attribute__((ext_vector_type(4))) float f32x4;
typedef __attribute__((ext_vector_type(8))) short bf16x8;

__device__ __forceinline__ short f2bf(float x) {
    __hip_bfloat16 h = __float2bfloat16(x);
    return __builtin_bit_cast(short, h);
}
__device__ __forceinline__ float bf2f(short u) {
    unsigned int x = ((unsigned int)(unsigned short)u) << 16;
    return __builtin_bit_cast(float, x);
}

__global__ void hist_kernel(const int* __restrict__ dst, int* __restrict__ cnt, int E) {
    int e = blockIdx.x * blockDim.x + threadIdx.x;
    if (e < E) atomicAdd(&cnt[dst[e]], 1);
}

// Phase 1: per-block (1024-node chunk) sums
__launch_bounds__(256)
__global__ void scan1_kernel(const int* __restrict__ cnt, int* __restrict__ bsum, int N) {
    __shared__ int red[256];
    int t = threadIdx.x;
    int base = blockIdx.x * CH + t * 4;
    int s = 0;
    for (int j = 0; j < 4; ++j)
        if (base + j < N) s += cnt[base + j];
    red[t] = s;
    __syncthreads();
    for (int off = 128; off > 0; off >>= 1) {
        if (t < off) red[t] += red[t + off];
        __syncthreads();
    }
    if (t == 0) bsum[blockIdx.x] = red[0];
}

// Phase 2: single tiny block scans the 98 block sums (exclusive) + writes rowp[N]
__launch_bounds__(128)
__global__ void scan2_kernel(const int* __restrict__ bsum, int* __restrict__ boff,
                             int* __restrict__ rowp, int nb, int N) {
    __shared__ int s[128];
    int t = threadIdx.x;
    int v = (t < nb) ? bsum[t] : 0;
    s[t] = v;
    __syncthreads();
    for (int off = 1; off < 128; off <<= 1) {
        int u = (t >= off) ? s[t - off] : 0;
        __syncthreads();
        s[t] += u;
        __syncthreads();
    }
    if (t < nb) boff[t] = s[t] - v;  // exclusive prefix
    if (t == 127) rowp[N] = s[127];
}

// Phase 3: local exclusive scan per chunk + global offset; emit rowp/cursor/norm
__launch_bounds__(256)
__global__ void scan3_kernel(const int* __restrict__ cnt, const int* __restrict__ boff,
                             int* __restrict__ rowp, int* __restrict__ cursor,
                             float* __restrict__ norm, int N) {
    __shared__ int sc[256];
    int t = threadIdx.x;
    int base = blockIdx.x * CH + t * 4;
    int c[4];
    int s = 0;
    for (int j = 0; j < 4; ++j) {
        c[j] = (base + j < N) ? cnt[base + j] : 0;
        s += c[j];
    }
    sc[t] = s;
    __syncthreads();
    for (int off = 1; off < 256; off <<= 1) {
        int u = (t >= off) ? sc[t - off] : 0;
        __syncthreads();
        sc[t] += u;
        __syncthreads();
    }
    int run = boff[blockIdx.x] + sc[t] - s;
    for (int j = 0; j < 4; ++j) {
        int i = base + j;
        if (i < N) {
            rowp[i] = run;
            cursor[i] = run;
            norm[i] = rsqrtf(fmaxf((float)c[j], 1.0f));
            run += c[j];
        }
    }
}

__global__ void fill_kernel(const int* __restrict__ src, const int* __restrict__ dst,
                            int* __restrict__ cursor, int* __restrict__ col, int E) {
    int e = blockIdx.x * blockDim.x + threadIdx.x;
    if (e < E) {
        int pos = atomicAdd(&cursor[dst[e]], 1);
        col[pos] = src[e];
    }
}

// xs = feat * norm[row], bf16 (halves gather traffic; folds src-norm weight)
__global__ void prescale_kernel(const float* __restrict__ feat, const float* __restrict__ norm,
                                short* __restrict__ xs, int Ntot) {
    int t = blockIdx.x * blockDim.x + threadIdx.x;
    if (t * 8 >= Ntot) return;
    float nm = norm[t >> 3];
    f32x4 a = *(const f32x4*)(feat + (size_t)t * 8);
    f32x4 b = *(const f32x4*)(feat + (size_t)t * 8 + 4);
    bf16x8 o;
    for (int j = 0; j < 4; ++j) {
        o[j] = f2bf(a[j] * nm);
        o[4 + j] = f2bf(b[j] * nm);
    }
    *(bf16x8*)(xs + (size_t)t * 8) = o;
}

// Pure bf16 row-sum gather: acc[n] = sum_{e: dst=n} in[src[e]] (f32 accumulate).
// MODE 0 (pass 1): o1 = Tx1 = C1A*norm[n]*acc   ; o2 = Tx1*norm[n]   (both bf16)
// MODE 1 (pass 2): o1 = acc (raw sum, bf16)
template <int MODE>
__launch_bounds__(256)
__global__ void gather_kernel(const short* __restrict__ xb, const float* __restrict__ norm,
                              const int* __restrict__ rowp, const int* __restrict__ col,
                              short* __restrict__ o1, short* __restrict__ o2, int N) {
    int n = blockIdx.x * 4 + (threadIdx.x >> 6);
    int lane = threadIdx.x & 63;
    if (n >= N) return;
    int beg = rowp[n];
    int end = rowp[n + 1];
    float acc = 0.0f;
    for (int base = beg; base < end; base += 64) {
        int m = min(64, end - base);
        int idx = (lane < m) ? col[base + lane] : 0;
#pragma unroll 4
        for (int t = 0; t < m; ++t) {
            int s = __shfl(idx, t);
            acc += bf2f(xb[(size_t)s * DD + lane]);
        }
    }
    size_t o = (size_t)n * DD + lane;
    if (MODE == 0) {
        float nm = norm[n];
        float tx1 = C1A * nm * acc;
        o1[o] = f2bf(tx1);
        o2[o] = f2bf(tx1 * nm);
    } else {
        o1[o] = f2bf(acc);
    }
}

// out = x0@W0 + Tx1@W1 + Tx2@W2 + bias;  Tx2 = C2A*norm[n]*t2sum + C2B*Tx1 - x0
__launch_bounds__(256)
__global__ void out_kernel(const float* __restrict__ feat,
                           const short* __restrict__ t1b,
                           const short* __restrict__ t2s,
                           const float* __restrict__ norm,
                           const float* __restrict__ W,
                           const float* __restrict__ bias,
                           float* __restrict__ out, int N) {
    // W transposed to [mat][n][k] in bf16, rows padded 64->72 (2-way banks, free)
    __shared__ __align__(16) short sW[3][64][72];
    for (int idx = threadIdx.x; idx < 3 * 64 * 64; idx += 256) {
        int m = idx >> 12;
        int r = idx & 4095;
        int k = r >> 6;
        int n = r & 63;
        sW[m][n][k] = f2bf(W[idx]);  // W flat = m*4096 + k*64 + n
    }
    __syncthreads();

    int wave = threadIdx.x >> 6;
    int lane = threadIdx.x & 63;
    int rowtile = blockIdx.x * 64 + wave * 16;
    if (rowtile >= N) return;
    int lrow = lane & 15;
    int lk = (lane >> 4) << 3;  // 0,8,16,24
    int row = rowtile + lrow;
    bool rv = row < N;
    float nrm = rv ? norm[row] : 0.0f;

    bf16x8 a[3][2];
    for (int s = 0; s < 2; ++s) {
        if (rv) {
            size_t base = (size_t)row * DD + s * 32 + lk;
            f32x4 fa = *(const f32x4*)(feat + base);
            f32x4 fb = *(const f32x4*)(feat + base + 4);
            bf16x8 t1v = *(const bf16x8*)(t1b + base);
            bf16x8 t2v = *(const bf16x8*)(t2s + base);
            a[1][s] = t1v;
            for (int j = 0; j < 8; ++j) {
                float xf = (j < 4) ? fa[j] : fb[j - 4];
                float T2 = C2A * nrm * bf2f(t2v[j]) - xf;
                if (C2B != 0.0f) T2 += C2B * bf2f(t1v[j]);
                a[0][s][j] = f2bf(xf);
                a[2][s][j] = f2bf(T2);
            }
        } else {
            for (int j = 0; j < 8; ++j) { a[0][s][j] = 0; a[1][s][j] = 0; a[2][s][j] = 0; }
        }
    }

    f32x4 acc[4];
    for (int ct = 0; ct < 4; ++ct) acc[ct] = (f32x4){0.f, 0.f, 0.f, 0.f};

    for (int m = 0; m < 3; ++m)
        for (int s = 0; s < 2; ++s)
            for (int ct = 0; ct < 4; ++ct) {
                bf16x8 b = *(const bf16x8*)&sW[m][ct * 16 + lrow][s * 32 + lk];
                acc[ct] = __builtin_amdgcn_mfma_f32_16x16x32_bf16(a[m][s], b, acc[ct], 0, 0, 0);
            }

    // C/D layout: col = lane&15, row = (lane>>4)*4 + reg  [verified m89/m91]
    int rbase = rowtile + ((lane >> 4) << 2);
    for (int ct = 0; ct < 4; ++ct) {
        int colo = ct * 16 + lrow;
        float bv = bias[colo];
        for (int r = 0; r < 4; ++r) {
            int ro = rbase + r;
            if (ro < N) out[(size_t)ro * DD + colo] = acc[ct][r] + bv;
        }
    }
}

extern "C" void kernel_launch(void* const* d_in, const int* in_sizes, int n_in,
                              void* d_out, int out_size, void* d_ws, size_t ws_size,
                              hipStream_t stream) {
    const float* feat = (const float*)d_in[0];
    const float* W    = (const float*)d_in[1];
    const float* bias = (const float*)d_in[2];
    const int* esrc   = (const int*)d_in[3];
    const int* edst   = (const int*)d_in[4];
    float* out = (float*)d_out;

    char* ws = (char*)d_ws;
    size_t off = 0;
    auto alloc = [&](size_t bytes) {
        void* p = ws + off;
        off = (off + bytes + 255) & ~(size_t)255;
        return p;
    };
    int*   cnt    = (int*)alloc((size_t)NN * 4);
    int*   rowp   = (int*)alloc(((size_t)NN + 1) * 4);
    int*   cursor = (int*)alloc((size_t)NN * 4);
    float* norm   = (float*)alloc((size_t)NN * 4);
    int*   bsum   = (int*)alloc((size_t)NB * 4);
    int*   boff   = (int*)alloc((size_t)NB * 4);
    int*   col    = (int*)alloc((size_t)NE * 4);
    short* xs     = (short*)alloc((size_t)NN * DD * 2);
    short* t1b    = (short*)alloc((size_t)NN * DD * 2);
    short* t1s    = (short*)alloc((size_t)NN * DD * 2);
    short* t2s    = (short*)alloc((size_t)NN * DD * 2);

    hipMemsetAsync(cnt, 0, (size_t)NN * 4, stream);

    hist_kernel<<<(NE + 255) / 256, 256, 0, stream>>>(edst, cnt, NE);
    scan1_kernel<<<NB, 256, 0, stream>>>(cnt, bsum, NN);
    scan2_kernel<<<1, 128, 0, stream>>>(bsum, boff, rowp, NB, NN);
    scan3_kernel<<<NB, 256, 0, stream>>>(cnt, boff, rowp, cursor, norm, NN);
    prescale_kernel<<<(NN * DD / 8 + 255) / 256, 256, 0, stream>>>(feat, norm, xs, NN * DD);
    fill_kernel<<<(NE + 255) / 256, 256, 0, stream>>>(esrc, edst, cursor, col, NE);
    gather_kernel<0><<<(NN + 3) / 4, 256, 0, stream>>>(xs, norm, rowp, col, t1b, t1s, NN);
    gather_kernel<1><<<(NN + 3) / 4, 256, 0, stream>>>(t1s, norm, rowp, col, t2s, nullptr, NN);
    out_kernel<<<(NN + 63) / 64, 256, 0, stream>>>(feat, t1b, t2s, norm, W, bias, out, NN);
}

// Round 4
// 312.995 us; speedup vs baseline: 2.6255x; 1.3477x over previous
//
#include <hip/hip_runtime.h>
#include <hip/hip_bf16.h>

#define NN 100000
#define NE 1600000
#define DD 64
#define BN 256                       // nodes per bucket (bucket = dst >> 8)
#define NBK ((NN + BN - 1) / BN)     // 391 buckets
#define EPB 16384                    // edges per block in partition passes
#define ABL ((NE + EPB - 1) / EPB)   // 98 blocks
#define EPT (EPB / 256)              // 64 edges per thread

constexpr float LAM = 2.0f;
constexpr float C1A = -2.0f / LAM;        // -1
constexpr float C1B = 2.0f / LAM - 1.0f;  //  0
constexpr float C2A = -4.0f / LAM;        // -2
constexpr float C2B = 4.0f / LAM - 2.0f;  //  0

typedef __attribute__((ext_vector_type(4))) float f32x4;
typedef __attribute__((ext_vector_type(8))) short bf16x8;

__device__ __forceinline__ short f2bf(float x) {
    __hip_bfloat16 h = __float2bfloat16(x);
    return __builtin_bit_cast(short, h);
}
__device__ __forceinline__ float bf2f(short u) {
    unsigned int x = ((unsigned int)(unsigned short)u) << 16;
    return __builtin_bit_cast(float, x);
}

// ---- bucketed CSR build -------------------------------------------------

__launch_bounds__(256)
__global__ void bhist_kernel(const int* __restrict__ dst, int* __restrict__ bcnt, int E) {
    __shared__ int lcnt[NBK];
    int t = threadIdx.x;
    for (int i = t; i < NBK; i += 256) lcnt[i] = 0;
    __syncthreads();
    int base = blockIdx.x * EPB;
    for (int i = 0; i < EPT; ++i) {
        int e = base + i * 256 + t;
        if (e < E) atomicAdd(&lcnt[dst[e] >> 8], 1);
    }
    __syncthreads();
    for (int i = t; i < NBK; i += 256)
        if (lcnt[i]) atomicAdd(&bcnt[i], lcnt[i]);
}

__launch_bounds__(512)
__global__ void bscan_kernel(const int* __restrict__ bcnt, int* __restrict__ bbase,
                             int* __restrict__ bcur, int* __restrict__ rowp) {
    __shared__ int s[512];
    int t = threadIdx.x;
    int v = (t < NBK) ? bcnt[t] : 0;
    s[t] = v;
    __syncthreads();
    for (int off = 1; off < 512; off <<= 1) {
        int u = (t >= off) ? s[t - off] : 0;
        __syncthreads();
        s[t] += u;
        __syncthreads();
    }
    if (t < NBK) {
        int ex = s[t] - v;
        bbase[t] = ex;
        bcur[t] = ex;
    }
    if (t == 0) {
        bbase[NBK] = NE;
        rowp[NN] = NE;
    }
}

__launch_bounds__(256)
__global__ void bfill_kernel(const int* __restrict__ src, const int* __restrict__ dst,
                             int* __restrict__ bcur, int2* __restrict__ pairs, int E) {
    __shared__ int lcnt[NBK];
    __shared__ int lbase[NBK];
    int t = threadIdx.x;
    for (int i = t; i < NBK; i += 256) lcnt[i] = 0;
    __syncthreads();
    int base = blockIdx.x * EPB;
    for (int i = 0; i < EPT; ++i) {
        int e = base + i * 256 + t;
        if (e < E) atomicAdd(&lcnt[dst[e] >> 8], 1);
    }
    __syncthreads();
    for (int i = t; i < NBK; i += 256) {
        int c = lcnt[i];
        lbase[i] = c ? atomicAdd(&bcur[i], c) : 0;
    }
    __syncthreads();
    for (int i = t; i < NBK; i += 256) lcnt[i] = 0;  // reuse as local cursor
    __syncthreads();
    for (int i = 0; i < EPT; ++i) {
        int e = base + i * 256 + t;
        if (e < E) {
            int d = dst[e];
            int bk = d >> 8;
            int pos = lbase[bk] + atomicAdd(&lcnt[bk], 1);
            pairs[pos] = make_int2(src[e], d);
        }
    }
}

// one block per bucket: per-node hist -> scan -> rowp/norm -> col fill
__launch_bounds__(256)
__global__ void csr_build_kernel(const int2* __restrict__ pairs, const int* __restrict__ bbase,
                                 int* __restrict__ rowp, float* __restrict__ norm,
                                 int* __restrict__ col, int N) {
    __shared__ int lcnt[BN];
    __shared__ int lsc[BN];
    __shared__ int lcur[BN];
    int b = blockIdx.x;
    int t = threadIdx.x;
    int beg = bbase[b];
    int end = bbase[b + 1];
    lcnt[t] = 0;
    __syncthreads();
    for (int i = beg + t; i < end; i += 256)
        atomicAdd(&lcnt[pairs[i].y & (BN - 1)], 1);
    __syncthreads();
    int c = lcnt[t];
    lsc[t] = c;
    __syncthreads();
    for (int off = 1; off < 256; off <<= 1) {
        int u = (t >= off) ? lsc[t - off] : 0;
        __syncthreads();
        lsc[t] += u;
        __syncthreads();
    }
    int ex = lsc[t] - c;  // exclusive local prefix
    lcur[t] = ex;
    int node = b * BN + t;
    if (node < N) {
        rowp[node] = beg + ex;
        norm[node] = rsqrtf(fmaxf((float)c, 1.0f));
    }
    __syncthreads();
    for (int i = beg + t; i < end; i += 256) {
        int2 p = pairs[i];
        int pos = atomicAdd(&lcur[p.y & (BN - 1)], 1);
        col[beg + pos] = p.x;
    }
}

// ---- dense pipeline -----------------------------------------------------

// xs = feat * norm[row], bf16 (halves gather traffic; folds src-norm weight)
__global__ void prescale_kernel(const float* __restrict__ feat, const float* __restrict__ norm,
                                short* __restrict__ xs, int Ntot) {
    int t = blockIdx.x * blockDim.x + threadIdx.x;
    if (t * 8 >= Ntot) return;
    float nm = norm[t >> 3];
    f32x4 a = *(const f32x4*)(feat + (size_t)t * 8);
    f32x4 b = *(const f32x4*)(feat + (size_t)t * 8 + 4);
    bf16x8 o;
    for (int j = 0; j < 4; ++j) {
        o[j] = f2bf(a[j] * nm);
        o[4 + j] = f2bf(b[j] * nm);
    }
    *(bf16x8*)(xs + (size_t)t * 8) = o;
}

// Pure bf16 row-sum gather: acc[n] = sum_{e: dst=n} in[src[e]] (f32 accumulate).
// MODE 0: o1 = Tx1 = C1A*norm[n]*acc ; o2 = Tx1*norm[n]   (both bf16)
// MODE 1: o1 = acc (raw sum, bf16)
template <int MODE>
__launch_bounds__(256)
__global__ void gather_kernel(const short* __restrict__ xb, const float* __restrict__ norm,
                              const int* __restrict__ rowp, const int* __restrict__ col,
                              short* __restrict__ o1, short* __restrict__ o2, int N) {
    int n = blockIdx.x * 4 + (threadIdx.x >> 6);
    int lane = threadIdx.x & 63;
    if (n >= N) return;
    int beg = rowp[n];
    int end = rowp[n + 1];
    float acc = 0.0f;
    for (int base = beg; base < end; base += 64) {
        int m = min(64, end - base);
        int idx = (lane < m) ? col[base + lane] : 0;
#pragma unroll 4
        for (int t = 0; t < m; ++t) {
            int s = __shfl(idx, t);
            acc += bf2f(xb[(size_t)s * DD + lane]);
        }
    }
    size_t o = (size_t)n * DD + lane;
    if (MODE == 0) {
        float nm = norm[n];
        float tx1 = C1A * nm * acc;
        o1[o] = f2bf(tx1);
        o2[o] = f2bf(tx1 * nm);
    } else {
        o1[o] = f2bf(acc);
    }
}

// out = x0@W0 + Tx1@W1 + Tx2@W2 + bias;  Tx2 = C2A*norm[n]*t2sum + C2B*Tx1 - x0
__launch_bounds__(256)
__global__ void out_kernel(const float* __restrict__ feat,
                           const short* __restrict__ t1b,
                           const short* __restrict__ t2s,
                           const float* __restrict__ norm,
                           const float* __restrict__ W,
                           const float* __restrict__ bias,
                           float* __restrict__ out, int N) {
    __shared__ __align__(16) short sW[3][64][72];
    for (int idx = threadIdx.x; idx < 3 * 64 * 64; idx += 256) {
        int m = idx >> 12;
        int r = idx & 4095;
        int k = r >> 6;
        int n = r & 63;
        sW[m][n][k] = f2bf(W[idx]);  // W flat = m*4096 + k*64 + n
    }
    __syncthreads();

    int wave = threadIdx.x >> 6;
    int lane = threadIdx.x & 63;
    int rowtile = blockIdx.x * 64 + wave * 16;
    if (rowtile >= N) return;
    int lrow = lane & 15;
    int lk = (lane >> 4) << 3;  // 0,8,16,24
    int row = rowtile + lrow;
    bool rv = row < N;
    float nrm = rv ? norm[row] : 0.0f;

    bf16x8 a[3][2];
    for (int s = 0; s < 2; ++s) {
        if (rv) {
            size_t base = (size_t)row * DD + s * 32 + lk;
            f32x4 fa = *(const f32x4*)(feat + base);
            f32x4 fb = *(const f32x4*)(feat + base + 4);
            bf16x8 t1v = *(const bf16x8*)(t1b + base);
            bf16x8 t2v = *(const bf16x8*)(t2s + base);
            a[1][s] = t1v;
            for (int j = 0; j < 8; ++j) {
                float xf = (j < 4) ? fa[j] : fb[j - 4];
                float T2 = C2A * nrm * bf2f(t2v[j]) - xf;
                if (C2B != 0.0f) T2 += C2B * bf2f(t1v[j]);
                a[0][s][j] = f2bf(xf);
                a[2][s][j] = f2bf(T2);
            }
        } else {
            for (int j = 0; j < 8; ++j) { a[0][s][j] = 0; a[1][s][j] = 0; a[2][s][j] = 0; }
        }
    }

    f32x4 acc[4];
    for (int ct = 0; ct < 4; ++ct) acc[ct] = (f32x4){0.f, 0.f, 0.f, 0.f};

    for (int m = 0; m < 3; ++m)
        for (int s = 0; s < 2; ++s)
            for (int ct = 0; ct < 4; ++ct) {
                bf16x8 bfr = *(const bf16x8*)&sW[m][ct * 16 + lrow][s * 32 + lk];
                acc[ct] = __builtin_amdgcn_mfma_f32_16x16x32_bf16(a[m][s], bfr, acc[ct], 0, 0, 0);
            }

    // C/D layout: col = lane&15, row = (lane>>4)*4 + reg  [verified m89/m91]
    int rbase = rowtile + ((lane >> 4) << 2);
    for (int ct = 0; ct < 4; ++ct) {
        int colo = ct * 16 + lrow;
        float bv = bias[colo];
        for (int r = 0; r < 4; ++r) {
            int ro = rbase + r;
            if (ro < N) out[(size_t)ro * DD + colo] = acc[ct][r] + bv;
        }
    }
}

extern "C" void kernel_launch(void* const* d_in, const int* in_sizes, int n_in,
                              void* d_out, int out_size, void* d_ws, size_t ws_size,
                              hipStream_t stream) {
    const float* feat = (const float*)d_in[0];
    const float* W    = (const float*)d_in[1];
    const float* bias = (const float*)d_in[2];
    const int* esrc   = (const int*)d_in[3];
    const int* edst   = (const int*)d_in[4];
    float* out = (float*)d_out;

    char* ws = (char*)d_ws;
    size_t off = 0;
    auto alloc = [&](size_t bytes) {
        void* p = ws + off;
        off = (off + bytes + 255) & ~(size_t)255;
        return p;
    };
    int*   rowp  = (int*)alloc(((size_t)NN + 1) * 4);
    float* norm  = (float*)alloc((size_t)NN * 4);
    int*   bcnt  = (int*)alloc((size_t)NBK * 4);
    int*   bbase = (int*)alloc(((size_t)NBK + 1) * 4);
    int*   bcur  = (int*)alloc((size_t)NBK * 4);
    int*   col   = (int*)alloc((size_t)NE * 4);
    int2*  pairs = (int2*)alloc((size_t)NE * 8);
    short* xs    = (short*)pairs;  // alias: pairs dead after csr_build (12.8MB each)
    short* t1b   = (short*)alloc((size_t)NN * DD * 2);
    short* t1s   = (short*)alloc((size_t)NN * DD * 2);
    short* t2s   = (short*)alloc((size_t)NN * DD * 2);

    hipMemsetAsync(bcnt, 0, (size_t)NBK * 4, stream);

    bhist_kernel<<<ABL, 256, 0, stream>>>(edst, bcnt, NE);
    bscan_kernel<<<1, 512, 0, stream>>>(bcnt, bbase, bcur, rowp);
    bfill_kernel<<<ABL, 256, 0, stream>>>(esrc, edst, bcur, pairs, NE);
    csr_build_kernel<<<NBK, 256, 0, stream>>>(pairs, bbase, rowp, norm, col, NN);
    prescale_kernel<<<(NN * DD / 8 + 255) / 256, 256, 0, stream>>>(feat, norm, xs, NN * DD);
    gather_kernel<0><<<(NN + 3) / 4, 256, 0, stream>>>(xs, norm, rowp, col, t1b, t1s, NN);
    gather_kernel<1><<<(NN + 3) / 4, 256, 0, stream>>>(t1s, norm, rowp, col, t2s, nullptr, NN);
    out_kernel<<<(NN + 63) / 64, 256, 0, stream>>>(feat, t1b, t2s, norm, W, bias, out, NN);
}

// Round 5
// 226.040 us; speedup vs baseline: 3.6355x; 1.3847x over previous
//
#include <hip/hip_runtime.h>
#include <hip/hip_bf16.h>

#define NN 100000
#define NE 1600000
#define DD 64
#define BN 256                       // nodes per bucket (bucket = dst >> 8)
#define NBK ((NN + BN - 1) / BN)     // 391 buckets
#define EPB 16384                    // edges per block in partition passes
#define ABL ((NE + EPB - 1) / EPB)   // 98 blocks
#define EPT (EPB / 256)              // 64 edges per thread

constexpr float LAM = 2.0f;
constexpr float C1A = -2.0f / LAM;        // -1
constexpr float C1B = 2.0f / LAM - 1.0f;  //  0
constexpr float C2A = -4.0f / LAM;        // -2
constexpr float C2B = 4.0f / LAM - 2.0f;  //  0

typedef __attribute__((ext_vector_type(4))) float f32x4;
typedef __attribute__((ext_vector_type(8))) short bf16x8;
typedef __attribute__((ext_vector_type(4))) short bf16x4;
typedef __attribute__((ext_vector_type(2))) unsigned int u32x2;

__device__ __forceinline__ short f2bf(float x) {
    __hip_bfloat16 h = __float2bfloat16(x);
    return __builtin_bit_cast(short, h);
}
__device__ __forceinline__ float bf2f(short u) {
    unsigned int x = ((unsigned int)(unsigned short)u) << 16;
    return __builtin_bit_cast(float, x);
}

// ---- bucketed CSR build -------------------------------------------------

__launch_bounds__(256)
__global__ void bhist_kernel(const int* __restrict__ dst, int* __restrict__ bcnt, int E) {
    __shared__ int lcnt[NBK];
    int t = threadIdx.x;
    for (int i = t; i < NBK; i += 256) lcnt[i] = 0;
    __syncthreads();
    int base = blockIdx.x * EPB;
    for (int i = 0; i < EPT; ++i) {
        int e = base + i * 256 + t;
        if (e < E) atomicAdd(&lcnt[dst[e] >> 8], 1);
    }
    __syncthreads();
    for (int i = t; i < NBK; i += 256)
        if (lcnt[i]) atomicAdd(&bcnt[i], lcnt[i]);
}

__launch_bounds__(512)
__global__ void bscan_kernel(const int* __restrict__ bcnt, int* __restrict__ bbase,
                             int* __restrict__ bcur, int* __restrict__ rowp) {
    __shared__ int s[512];
    int t = threadIdx.x;
    int v = (t < NBK) ? bcnt[t] : 0;
    s[t] = v;
    __syncthreads();
    for (int off = 1; off < 512; off <<= 1) {
        int u = (t >= off) ? s[t - off] : 0;
        __syncthreads();
        s[t] += u;
        __syncthreads();
    }
    if (t < NBK) {
        int ex = s[t] - v;
        bbase[t] = ex;
        bcur[t] = ex;
    }
    if (t == 0) {
        bbase[NBK] = NE;
        rowp[NN] = NE;
    }
}

__launch_bounds__(256)
__global__ void bfill_kernel(const int* __restrict__ src, const int* __restrict__ dst,
                             int* __restrict__ bcur, unsigned* __restrict__ pairs, int E) {
    __shared__ int lcnt[NBK];
    __shared__ int lbase[NBK];
    int t = threadIdx.x;
    for (int i = t; i < NBK; i += 256) lcnt[i] = 0;
    __syncthreads();
    int base = blockIdx.x * EPB;
    for (int i = 0; i < EPT; ++i) {
        int e = base + i * 256 + t;
        if (e < E) atomicAdd(&lcnt[dst[e] >> 8], 1);
    }
    __syncthreads();
    for (int i = t; i < NBK; i += 256) {
        int c = lcnt[i];
        lbase[i] = c ? atomicAdd(&bcur[i], c) : 0;
    }
    __syncthreads();
    for (int i = t; i < NBK; i += 256) lcnt[i] = 0;  // reuse as local cursor
    __syncthreads();
    for (int i = 0; i < EPT; ++i) {
        int e = base + i * 256 + t;
        if (e < E) {
            int d = dst[e];
            int bk = d >> 8;
            int pos = lbase[bk] + atomicAdd(&lcnt[bk], 1);
            pairs[pos] = ((unsigned)src[e] << 8) | (unsigned)(d & 255);  // src<2^24
        }
    }
}

// one block per bucket: per-node hist -> scan -> rowp/norm -> col fill
__launch_bounds__(256)
__global__ void csr_build_kernel(const unsigned* __restrict__ pairs, const int* __restrict__ bbase,
                                 int* __restrict__ rowp, float* __restrict__ norm,
                                 int* __restrict__ col, int N) {
    __shared__ int lcnt[BN];
    __shared__ int lsc[BN];
    __shared__ int lcur[BN];
    int b = blockIdx.x;
    int t = threadIdx.x;
    int beg = bbase[b];
    int end = bbase[b + 1];
    lcnt[t] = 0;
    __syncthreads();
    for (int i = beg + t; i < end; i += 256)
        atomicAdd(&lcnt[pairs[i] & (BN - 1)], 1);
    __syncthreads();
    int c = lcnt[t];
    lsc[t] = c;
    __syncthreads();
    for (int off = 1; off < 256; off <<= 1) {
        int u = (t >= off) ? lsc[t - off] : 0;
        __syncthreads();
        lsc[t] += u;
        __syncthreads();
    }
    int ex = lsc[t] - c;  // exclusive local prefix
    lcur[t] = ex;
    int node = b * BN + t;
    if (node < N) {
        rowp[node] = beg + ex;
        norm[node] = rsqrtf(fmaxf((float)c, 1.0f));
    }
    __syncthreads();
    for (int i = beg + t; i < end; i += 256) {
        unsigned p = pairs[i];
        int pos = atomicAdd(&lcur[p & (BN - 1)], 1);
        col[beg + pos] = (int)(p >> 8);
    }
}

// ---- dense pipeline -----------------------------------------------------

// xs = feat * norm[row], bf16 (halves gather traffic; folds src-norm weight)
__global__ void prescale_kernel(const float* __restrict__ feat, const float* __restrict__ norm,
                                short* __restrict__ xs, int Ntot) {
    int t = blockIdx.x * blockDim.x + threadIdx.x;
    if (t * 8 >= Ntot) return;
    float nm = norm[t >> 3];
    f32x4 a = *(const f32x4*)(feat + (size_t)t * 8);
    f32x4 b = *(const f32x4*)(feat + (size_t)t * 8 + 4);
    bf16x8 o;
    for (int j = 0; j < 4; ++j) {
        o[j] = f2bf(a[j] * nm);
        o[4 + j] = f2bf(b[j] * nm);
    }
    *(bf16x8*)(xs + (size_t)t * 8) = o;
}

// Row-sum gather, 4 edges/iteration: 16-lane group g handles edge eb+g,
// each lane loads 8B (4 bf16 dims). f32 accumulate; one butterfly per node.
// MODE 0: o1 = Tx1 = C1A*norm[n]*acc ; o2 = Tx1*norm[n]   (both bf16)
// MODE 1: o1 = acc (raw sum, bf16)
template <int MODE>
__launch_bounds__(256)
__global__ void gather_kernel(const short* __restrict__ xb, const float* __restrict__ norm,
                              const int* __restrict__ rowp, const int* __restrict__ col,
                              short* __restrict__ o1, short* __restrict__ o2, int N) {
    int n = blockIdx.x * 4 + (threadIdx.x >> 6);
    int lane = threadIdx.x & 63;
    if (n >= N) return;
    int g = lane >> 4;          // edge slot 0..3
    int dl = (lane & 15) << 2;  // dim base 0,4,..,60
    int beg = rowp[n];
    int end = rowp[n + 1];
    const short* rb = xb + dl;
    float a0 = 0.f, a1 = 0.f, a2 = 0.f, a3 = 0.f;
#pragma unroll 2
    for (int eb = beg; eb < end; eb += 4) {
        int e = eb + g;
        u32x2 v = {0u, 0u};
        if (e < end) {
            int s = col[e];
            v = *(const u32x2*)(rb + (size_t)s * DD);
        }
        a0 += __builtin_bit_cast(float, v[0] << 16);
        a1 += __builtin_bit_cast(float, v[0] & 0xffff0000u);
        a2 += __builtin_bit_cast(float, v[1] << 16);
        a3 += __builtin_bit_cast(float, v[1] & 0xffff0000u);
    }
    a0 += __shfl_xor(a0, 16); a0 += __shfl_xor(a0, 32);
    a1 += __shfl_xor(a1, 16); a1 += __shfl_xor(a1, 32);
    a2 += __shfl_xor(a2, 16); a2 += __shfl_xor(a2, 32);
    a3 += __shfl_xor(a3, 16); a3 += __shfl_xor(a3, 32);
    if (g == 0) {
        size_t o = (size_t)n * DD + dl;
        if (MODE == 0) {
            float nm = norm[n];
            float t0 = C1A * nm * a0, t1 = C1A * nm * a1;
            float t2 = C1A * nm * a2, t3 = C1A * nm * a3;
            bf16x4 r1 = {f2bf(t0), f2bf(t1), f2bf(t2), f2bf(t3)};
            *(bf16x4*)(o1 + o) = r1;
            bf16x4 r2 = {f2bf(t0 * nm), f2bf(t1 * nm), f2bf(t2 * nm), f2bf(t3 * nm)};
            *(bf16x4*)(o2 + o) = r2;
        } else {
            bf16x4 r = {f2bf(a0), f2bf(a1), f2bf(a2), f2bf(a3)};
            *(bf16x4*)(o1 + o) = r;
        }
    }
}

// out = x0@W0 + Tx1@W1 + Tx2@W2 + bias;  Tx2 = C2A*norm[n]*t2sum + C2B*Tx1 - x0
__launch_bounds__(256)
__global__ void out_kernel(const float* __restrict__ feat,
                           const short* __restrict__ t1b,
                           const short* __restrict__ t2s,
                           const float* __restrict__ norm,
                           const float* __restrict__ W,
                           const float* __restrict__ bias,
                           float* __restrict__ out, int N) {
    __shared__ __align__(16) short sW[3][64][72];
    for (int idx = threadIdx.x; idx < 3 * 64 * 64; idx += 256) {
        int m = idx >> 12;
        int r = idx & 4095;
        int k = r >> 6;
        int n = r & 63;
        sW[m][n][k] = f2bf(W[idx]);  // W flat = m*4096 + k*64 + n
    }
    __syncthreads();

    int wave = threadIdx.x >> 6;
    int lane = threadIdx.x & 63;
    int rowtile = blockIdx.x * 64 + wave * 16;
    if (rowtile >= N) return;
    int lrow = lane & 15;
    int lk = (lane >> 4) << 3;  // 0,8,16,24
    int row = rowtile + lrow;
    bool rv = row < N;
    float nrm = rv ? norm[row] : 0.0f;

    bf16x8 a[3][2];
    for (int s = 0; s < 2; ++s) {
        if (rv) {
            size_t base = (size_t)row * DD + s * 32 + lk;
            f32x4 fa = *(const f32x4*)(feat + base);
            f32x4 fb = *(const f32x4*)(feat + base + 4);
            bf16x8 t1v = *(const bf16x8*)(t1b + base);
            bf16x8 t2v = *(const bf16x8*)(t2s + base);
            a[1][s] = t1v;
            for (int j = 0; j < 8; ++j) {
                float xf = (j < 4) ? fa[j] : fb[j - 4];
                float T2 = C2A * nrm * bf2f(t2v[j]) - xf;
                if (C2B != 0.0f) T2 += C2B * bf2f(t1v[j]);
                a[0][s][j] = f2bf(xf);
                a[2][s][j] = f2bf(T2);
            }
        } else {
            for (int j = 0; j < 8; ++j) { a[0][s][j] = 0; a[1][s][j] = 0; a[2][s][j] = 0; }
        }
    }

    f32x4 acc[4];
    for (int ct = 0; ct < 4; ++ct) acc[ct] = (f32x4){0.f, 0.f, 0.f, 0.f};

    for (int m = 0; m < 3; ++m)
        for (int s = 0; s < 2; ++s)
            for (int ct = 0; ct < 4; ++ct) {
                bf16x8 bfr = *(const bf16x8*)&sW[m][ct * 16 + lrow][s * 32 + lk];
                acc[ct] = __builtin_amdgcn_mfma_f32_16x16x32_bf16(a[m][s], bfr, acc[ct], 0, 0, 0);
            }

    // C/D layout: col = lane&15, row = (lane>>4)*4 + reg  [verified m89/m91]
    int rbase = rowtile + ((lane >> 4) << 2);
    for (int ct = 0; ct < 4; ++ct) {
        int colo = ct * 16 + lrow;
        float bv = bias[colo];
        for (int r = 0; r < 4; ++r) {
            int ro = rbase + r;
            if (ro < N) out[(size_t)ro * DD + colo] = acc[ct][r] + bv;
        }
    }
}

extern "C" void kernel_launch(void* const* d_in, const int* in_sizes, int n_in,
                              void* d_out, int out_size, void* d_ws, size_t ws_size,
                              hipStream_t stream) {
    const float* feat = (const float*)d_in[0];
    const float* W    = (const float*)d_in[1];
    const float* bias = (const float*)d_in[2];
    const int* esrc   = (const int*)d_in[3];
    const int* edst   = (const int*)d_in[4];
    float* out = (float*)d_out;

    char* ws = (char*)d_ws;
    size_t off = 0;
    auto alloc = [&](size_t bytes) {
        void* p = ws + off;
        off = (off + bytes + 255) & ~(size_t)255;
        return p;
    };
    int*      rowp  = (int*)alloc(((size_t)NN + 1) * 4);
    float*    norm  = (float*)alloc((size_t)NN * 4);
    int*      bcnt  = (int*)alloc((size_t)NBK * 4);
    int*      bbase = (int*)alloc(((size_t)NBK + 1) * 4);
    int*      bcur  = (int*)alloc((size_t)NBK * 4);
    int*      col   = (int*)alloc((size_t)NE * 4);
    unsigned* pairs = (unsigned*)alloc((size_t)NE * 4);
    short*    xs    = (short*)alloc((size_t)NN * DD * 2);
    short*    t1b   = (short*)alloc((size_t)NN * DD * 2);
    short*    t1s   = (short*)alloc((size_t)NN * DD * 2);
    short*    t2s   = xs;  // alias: xs dead after gather<0>

    hipMemsetAsync(bcnt, 0, (size_t)NBK * 4, stream);

    bhist_kernel<<<ABL, 256, 0, stream>>>(edst, bcnt, NE);
    bscan_kernel<<<1, 512, 0, stream>>>(bcnt, bbase, bcur, rowp);
    bfill_kernel<<<ABL, 256, 0, stream>>>(esrc, edst, bcur, pairs, NE);
    csr_build_kernel<<<NBK, 256, 0, stream>>>(pairs, bbase, rowp, norm, col, NN);
    prescale_kernel<<<(NN * DD / 8 + 255) / 256, 256, 0, stream>>>(feat, norm, xs, NN * DD);
    gather_kernel<0><<<(NN + 3) / 4, 256, 0, stream>>>(xs, norm, rowp, col, t1b, t1s, NN);
    gather_kernel<1><<<(NN + 3) / 4, 256, 0, stream>>>(t1s, norm, rowp, col, t2s, nullptr, NN);
    out_kernel<<<(NN + 63) / 64, 256, 0, stream>>>(feat, t1b, t2s, norm, W, bias, out, NN);
}

// Round 6
// 187.903 us; speedup vs baseline: 4.3734x; 1.2030x over previous
//
#include <hip/hip_runtime.h>
#include <hip/hip_bf16.h>

#define NN 100000
#define NE 1600000
#define DD 64
#define BN 256                       // nodes per bucket (bucket = dst >> 8)
#define NBK ((NN + BN - 1) / BN)     // 391 buckets
#define PTH 512                      // threads per partition block
#define EPB 4096                     // edges per block in partition passes
#define ABL ((NE + EPB - 1) / EPB)   // 391 blocks
#define EPT (EPB / PTH)              // 8 edges per thread

constexpr float LAM = 2.0f;
constexpr float C1A = -2.0f / LAM;        // -1
constexpr float C1B = 2.0f / LAM - 1.0f;  //  0
constexpr float C2A = -4.0f / LAM;        // -2
constexpr float C2B = 4.0f / LAM - 2.0f;  //  0

typedef __attribute__((ext_vector_type(4))) float f32x4;
typedef __attribute__((ext_vector_type(8))) short bf16x8;
typedef __attribute__((ext_vector_type(4))) short bf16x4;
typedef __attribute__((ext_vector_type(2))) unsigned int u32x2;

__device__ __forceinline__ short f2bf(float x) {
    __hip_bfloat16 h = __float2bfloat16(x);
    return __builtin_bit_cast(short, h);
}
__device__ __forceinline__ float bf2f(short u) {
    unsigned int x = ((unsigned int)(unsigned short)u) << 16;
    return __builtin_bit_cast(float, x);
}

// ---- bucketed CSR build -------------------------------------------------

__launch_bounds__(PTH)
__global__ void bhist_kernel(const int* __restrict__ dst, int* __restrict__ bcnt, int E) {
    __shared__ int lcnt[NBK];
    int t = threadIdx.x;
    for (int i = t; i < NBK; i += PTH) lcnt[i] = 0;
    __syncthreads();
    int base = blockIdx.x * EPB;
    for (int i = 0; i < EPT; ++i) {
        int e = base + i * PTH + t;
        if (e < E) atomicAdd(&lcnt[dst[e] >> 8], 1);
    }
    __syncthreads();
    for (int i = t; i < NBK; i += PTH)
        if (lcnt[i]) atomicAdd(&bcnt[i], lcnt[i]);
}

__launch_bounds__(512)
__global__ void bscan_kernel(const int* __restrict__ bcnt, int* __restrict__ bbase,
                             int* __restrict__ bcur, int* __restrict__ rowp) {
    __shared__ int s[512];
    int t = threadIdx.x;
    int v = (t < NBK) ? bcnt[t] : 0;
    s[t] = v;
    __syncthreads();
    for (int off = 1; off < 512; off <<= 1) {
        int u = (t >= off) ? s[t - off] : 0;
        __syncthreads();
        s[t] += u;
        __syncthreads();
    }
    if (t < NBK) {
        int ex = s[t] - v;
        bbase[t] = ex;
        bcur[t] = ex;
    }
    if (t == 0) {
        bbase[NBK] = NE;
        rowp[NN] = NE;
    }
}

__launch_bounds__(PTH)
__global__ void bfill_kernel(const int* __restrict__ src, const int* __restrict__ dst,
                             int* __restrict__ bcur, unsigned* __restrict__ pairs, int E) {
    __shared__ int lcnt[NBK];
    __shared__ int lbase[NBK];
    int t = threadIdx.x;
    for (int i = t; i < NBK; i += PTH) lcnt[i] = 0;
    __syncthreads();
    int base = blockIdx.x * EPB;
    for (int i = 0; i < EPT; ++i) {
        int e = base + i * PTH + t;
        if (e < E) atomicAdd(&lcnt[dst[e] >> 8], 1);
    }
    __syncthreads();
    for (int i = t; i < NBK; i += PTH) {
        int c = lcnt[i];
        lbase[i] = c ? atomicAdd(&bcur[i], c) : 0;
    }
    __syncthreads();
    for (int i = t; i < NBK; i += PTH) lcnt[i] = 0;  // reuse as local cursor
    __syncthreads();
    for (int i = 0; i < EPT; ++i) {
        int e = base + i * PTH + t;
        if (e < E) {
            int d = dst[e];
            int bk = d >> 8;
            int pos = lbase[bk] + atomicAdd(&lcnt[bk], 1);
            pairs[pos] = ((unsigned)src[e] << 8) | (unsigned)(d & 255);  // src<2^24
        }
    }
}

// one block per bucket: per-node hist -> scan -> rowp/norm -> col fill
__launch_bounds__(512)
__global__ void csr_build_kernel(const unsigned* __restrict__ pairs, const int* __restrict__ bbase,
                                 int* __restrict__ rowp, float* __restrict__ norm,
                                 int* __restrict__ col, int N) {
    __shared__ int lcnt[BN];
    __shared__ int lsc[BN];
    __shared__ int lcur[BN];
    int b = blockIdx.x;
    int t = threadIdx.x;
    int beg = bbase[b];
    int end = bbase[b + 1];
    if (t < BN) lcnt[t] = 0;
    __syncthreads();
    for (int i = beg + t; i < end; i += 512)
        atomicAdd(&lcnt[pairs[i] & (BN - 1)], 1);
    __syncthreads();
    int c = (t < BN) ? lcnt[t] : 0;
    if (t < BN) lsc[t] = c;
    __syncthreads();
    for (int off = 1; off < BN; off <<= 1) {
        int u = (t < BN && t >= off) ? lsc[t - off] : 0;
        __syncthreads();
        if (t < BN) lsc[t] += u;
        __syncthreads();
    }
    if (t < BN) {
        int ex = lsc[t] - c;  // exclusive local prefix
        lcur[t] = ex;
        int node = b * BN + t;
        if (node < N) {
            rowp[node] = beg + ex;
            norm[node] = rsqrtf(fmaxf((float)c, 1.0f));
        }
    }
    __syncthreads();
    for (int i = beg + t; i < end; i += 512) {
        unsigned p = pairs[i];
        int pos = atomicAdd(&lcur[p & (BN - 1)], 1);
        col[beg + pos] = (int)(p >> 8);
    }
}

// ---- dense pipeline -----------------------------------------------------

// xs = feat * norm[row], bf16 (halves gather traffic; folds src-norm weight)
__global__ void prescale_kernel(const float* __restrict__ feat, const float* __restrict__ norm,
                                short* __restrict__ xs, int Ntot) {
    int t = blockIdx.x * blockDim.x + threadIdx.x;
    if (t * 8 >= Ntot) return;
    float nm = norm[t >> 3];
    f32x4 a = *(const f32x4*)(feat + (size_t)t * 8);
    f32x4 b = *(const f32x4*)(feat + (size_t)t * 8 + 4);
    bf16x8 o;
    for (int j = 0; j < 4; ++j) {
        o[j] = f2bf(a[j] * nm);
        o[4 + j] = f2bf(b[j] * nm);
    }
    *(bf16x8*)(xs + (size_t)t * 8) = o;
}

// Row-sum gather, 4 edges/iteration: 16-lane group g handles edge eb+g,
// each lane loads 8B (4 bf16 dims). f32 accumulate; one butterfly per node.
// MODE 0: o1 = Tx1 = C1A*norm[n]*acc ; o2 = Tx1*norm[n]   (both bf16)
// MODE 1: o1 = acc (raw sum, bf16)
template <int MODE>
__launch_bounds__(256)
__global__ void gather_kernel(const short* __restrict__ xb, const float* __restrict__ norm,
                              const int* __restrict__ rowp, const int* __restrict__ col,
                              short* __restrict__ o1, short* __restrict__ o2, int N) {
    int n = blockIdx.x * 4 + (threadIdx.x >> 6);
    int lane = threadIdx.x & 63;
    if (n >= N) return;
    int g = lane >> 4;          // edge slot 0..3
    int dl = (lane & 15) << 2;  // dim base 0,4,..,60
    int beg = rowp[n];
    int end = rowp[n + 1];
    const short* rb = xb + dl;
    float a0 = 0.f, a1 = 0.f, a2 = 0.f, a3 = 0.f;
#pragma unroll 2
    for (int eb = beg; eb < end; eb += 4) {
        int e = eb + g;
        u32x2 v = {0u, 0u};
        if (e < end) {
            int s = col[e];
            v = *(const u32x2*)(rb + (size_t)s * DD);
        }
        a0 += __builtin_bit_cast(float, v[0] << 16);
        a1 += __builtin_bit_cast(float, v[0] & 0xffff0000u);
        a2 += __builtin_bit_cast(float, v[1] << 16);
        a3 += __builtin_bit_cast(float, v[1] & 0xffff0000u);
    }
    a0 += __shfl_xor(a0, 16); a0 += __shfl_xor(a0, 32);
    a1 += __shfl_xor(a1, 16); a1 += __shfl_xor(a1, 32);
    a2 += __shfl_xor(a2, 16); a2 += __shfl_xor(a2, 32);
    a3 += __shfl_xor(a3, 16); a3 += __shfl_xor(a3, 32);
    if (g == 0) {
        size_t o = (size_t)n * DD + dl;
        if (MODE == 0) {
            float nm = norm[n];
            float t0 = C1A * nm * a0, t1 = C1A * nm * a1;
            float t2 = C1A * nm * a2, t3 = C1A * nm * a3;
            bf16x4 r1 = {f2bf(t0), f2bf(t1), f2bf(t2), f2bf(t3)};
            *(bf16x4*)(o1 + o) = r1;
            bf16x4 r2 = {f2bf(t0 * nm), f2bf(t1 * nm), f2bf(t2 * nm), f2bf(t3 * nm)};
            *(bf16x4*)(o2 + o) = r2;
        } else {
            bf16x4 r = {f2bf(a0), f2bf(a1), f2bf(a2), f2bf(a3)};
            *(bf16x4*)(o1 + o) = r;
        }
    }
}

// out = x0@W0 + Tx1@W1 + Tx2@W2 + bias;  Tx2 = C2A*norm[n]*t2sum + C2B*Tx1 - x0
__launch_bounds__(256)
__global__ void out_kernel(const float* __restrict__ feat,
                           const short* __restrict__ t1b,
                           const short* __restrict__ t2s,
                           const float* __restrict__ norm,
                           const float* __restrict__ W,
                           const float* __restrict__ bias,
                           float* __restrict__ out, int N) {
    __shared__ __align__(16) short sW[3][64][72];
    for (int idx = threadIdx.x; idx < 3 * 64 * 64; idx += 256) {
        int m = idx >> 12;
        int r = idx & 4095;
        int k = r >> 6;
        int n = r & 63;
        sW[m][n][k] = f2bf(W[idx]);  // W flat = m*4096 + k*64 + n
    }
    __syncthreads();

    int wave = threadIdx.x >> 6;
    int lane = threadIdx.x & 63;
    int rowtile = blockIdx.x * 64 + wave * 16;
    if (rowtile >= N) return;
    int lrow = lane & 15;
    int lk = (lane >> 4) << 3;  // 0,8,16,24
    int row = rowtile + lrow;
    bool rv = row < N;
    float nrm = rv ? norm[row] : 0.0f;

    bf16x8 a[3][2];
    for (int s = 0; s < 2; ++s) {
        if (rv) {
            size_t base = (size_t)row * DD + s * 32 + lk;
            f32x4 fa = *(const f32x4*)(feat + base);
            f32x4 fb = *(const f32x4*)(feat + base + 4);
            bf16x8 t1v = *(const bf16x8*)(t1b + base);
            bf16x8 t2v = *(const bf16x8*)(t2s + base);
            a[1][s] = t1v;
            for (int j = 0; j < 8; ++j) {
                float xf = (j < 4) ? fa[j] : fb[j - 4];
                float T2 = C2A * nrm * bf2f(t2v[j]) - xf;
                if (C2B != 0.0f) T2 += C2B * bf2f(t1v[j]);
                a[0][s][j] = f2bf(xf);
                a[2][s][j] = f2bf(T2);
            }
        } else {
            for (int j = 0; j < 8; ++j) { a[0][s][j] = 0; a[1][s][j] = 0; a[2][s][j] = 0; }
        }
    }

    f32x4 acc[4];
    for (int ct = 0; ct < 4; ++ct) acc[ct] = (f32x4){0.f, 0.f, 0.f, 0.f};

    for (int m = 0; m < 3; ++m)
        for (int s = 0; s < 2; ++s)
            for (int ct = 0; ct < 4; ++ct) {
                bf16x8 bfr = *(const bf16x8*)&sW[m][ct * 16 + lrow][s * 32 + lk];
                acc[ct] = __builtin_amdgcn_mfma_f32_16x16x32_bf16(a[m][s], bfr, acc[ct], 0, 0, 0);
            }

    // C/D layout: col = lane&15, row = (lane>>4)*4 + reg  [verified m89/m91]
    int rbase = rowtile + ((lane >> 4) << 2);
    for (int ct = 0; ct < 4; ++ct) {
        int colo = ct * 16 + lrow;
        float bv = bias[colo];
        for (int r = 0; r < 4; ++r) {
            int ro = rbase + r;
            if (ro < N) out[(size_t)ro * DD + colo] = acc[ct][r] + bv;
        }
    }
}

extern "C" void kernel_launch(void* const* d_in, const int* in_sizes, int n_in,
                              void* d_out, int out_size, void* d_ws, size_t ws_size,
                              hipStream_t stream) {
    const float* feat = (const float*)d_in[0];
    const float* W    = (const float*)d_in[1];
    const float* bias = (const float*)d_in[2];
    const int* esrc   = (const int*)d_in[3];
    const int* edst   = (const int*)d_in[4];
    float* out = (float*)d_out;

    char* ws = (char*)d_ws;
    size_t off = 0;
    auto alloc = [&](size_t bytes) {
        void* p = ws + off;
        off = (off + bytes + 255) & ~(size_t)255;
        return p;
    };
    int*      rowp  = (int*)alloc(((size_t)NN + 1) * 4);
    float*    norm  = (float*)alloc((size_t)NN * 4);
    int*      bcnt  = (int*)alloc((size_t)NBK * 4);
    int*      bbase = (int*)alloc(((size_t)NBK + 1) * 4);
    int*      bcur  = (int*)alloc((size_t)NBK * 4);
    int*      col   = (int*)alloc((size_t)NE * 4);
    unsigned* pairs = (unsigned*)alloc((size_t)NE * 4);
    short*    xs    = (short*)alloc((size_t)NN * DD * 2);
    short*    t1b   = (short*)alloc((size_t)NN * DD * 2);
    short*    t1s   = (short*)alloc((size_t)NN * DD * 2);
    short*    t2s   = xs;  // alias: xs dead after gather<0>

    hipMemsetAsync(bcnt, 0, (size_t)NBK * 4, stream);

    bhist_kernel<<<ABL, PTH, 0, stream>>>(edst, bcnt, NE);
    bscan_kernel<<<1, 512, 0, stream>>>(bcnt, bbase, bcur, rowp);
    bfill_kernel<<<ABL, PTH, 0, stream>>>(esrc, edst, bcur, pairs, NE);
    csr_build_kernel<<<NBK, 512, 0, stream>>>(pairs, bbase, rowp, norm, col, NN);
    prescale_kernel<<<(NN * DD / 8 + 255) / 256, 256, 0, stream>>>(feat, norm, xs, NN * DD);
    gather_kernel<0><<<(NN + 3) / 4, 256, 0, stream>>>(xs, norm, rowp, col, t1b, t1s, NN);
    gather_kernel<1><<<(NN + 3) / 4, 256, 0, stream>>>(t1s, norm, rowp, col, t2s, nullptr, NN);
    out_kernel<<<(NN + 63) / 64, 256, 0, stream>>>(feat, t1b, t2s, norm, W, bias, out, NN);
}

// Round 7
// 183.693 us; speedup vs baseline: 4.4736x; 1.0229x over previous
//
#include <hip/hip_runtime.h>
#include <hip/hip_bf16.h>

#define NN 100000
#define NE 1600000
#define DD 64
#define BN 256                       // nodes per bucket (bucket = dst >> 8)
#define NBK ((NN + BN - 1) / BN)     // 391 buckets
#define PTH 512                      // threads per partition block
#define EPB 4096                     // edges per block in partition passes
#define ABL ((NE + EPB - 1) / EPB)   // 391 blocks
#define EPT (EPB / PTH)              // 8 edges per thread

constexpr float LAM = 2.0f;
constexpr float C1A = -2.0f / LAM;        // -1
constexpr float C1B = 2.0f / LAM - 1.0f;  //  0
constexpr float C2A = -4.0f / LAM;        // -2
constexpr float C2B = 4.0f / LAM - 2.0f;  //  0

typedef __attribute__((ext_vector_type(4))) float f32x4;
typedef __attribute__((ext_vector_type(8))) short bf16x8;
typedef __attribute__((ext_vector_type(4))) short bf16x4;
typedef __attribute__((ext_vector_type(2))) unsigned int u32x2;

__device__ __forceinline__ short f2bf(float x) {
    __hip_bfloat16 h = __float2bfloat16(x);
    return __builtin_bit_cast(short, h);
}
__device__ __forceinline__ float bf2f(short u) {
    unsigned int x = ((unsigned int)(unsigned short)u) << 16;
    return __builtin_bit_cast(float, x);
}

// ---- bucketed CSR build -------------------------------------------------

__launch_bounds__(PTH)
__global__ void bhist_kernel(const int* __restrict__ dst, int* __restrict__ bcnt, int E) {
    __shared__ int lcnt[NBK];
    int t = threadIdx.x;
    for (int i = t; i < NBK; i += PTH) lcnt[i] = 0;
    __syncthreads();
    int base = blockIdx.x * EPB;
    for (int i = 0; i < EPT; ++i) {
        int e = base + i * PTH + t;
        if (e < E) atomicAdd(&lcnt[dst[e] >> 8], 1);
    }
    __syncthreads();
    for (int i = t; i < NBK; i += PTH)
        if (lcnt[i]) atomicAdd(&bcnt[i], lcnt[i]);
}

__launch_bounds__(512)
__global__ void bscan_kernel(const int* __restrict__ bcnt, int* __restrict__ bbase,
                             int* __restrict__ bcur, int* __restrict__ rowp) {
    __shared__ int s[512];
    int t = threadIdx.x;
    int v = (t < NBK) ? bcnt[t] : 0;
    s[t] = v;
    __syncthreads();
    for (int off = 1; off < 512; off <<= 1) {
        int u = (t >= off) ? s[t - off] : 0;
        __syncthreads();
        s[t] += u;
        __syncthreads();
    }
    if (t < NBK) {
        int ex = s[t] - v;
        bbase[t] = ex;
        bcur[t] = ex;
    }
    if (t == 0) {
        bbase[NBK] = NE;
        rowp[NN] = NE;
    }
}

__launch_bounds__(PTH)
__global__ void bfill_kernel(const int* __restrict__ src, const int* __restrict__ dst,
                             int* __restrict__ bcur, unsigned* __restrict__ pairs, int E) {
    __shared__ int lcnt[NBK];
    __shared__ int lbase[NBK];
    int t = threadIdx.x;
    for (int i = t; i < NBK; i += PTH) lcnt[i] = 0;
    __syncthreads();
    int base = blockIdx.x * EPB;
    for (int i = 0; i < EPT; ++i) {
        int e = base + i * PTH + t;
        if (e < E) atomicAdd(&lcnt[dst[e] >> 8], 1);
    }
    __syncthreads();
    for (int i = t; i < NBK; i += PTH) {
        int c = lcnt[i];
        lbase[i] = c ? atomicAdd(&bcur[i], c) : 0;
    }
    __syncthreads();
    for (int i = t; i < NBK; i += PTH) lcnt[i] = 0;  // reuse as local cursor
    __syncthreads();
    for (int i = 0; i < EPT; ++i) {
        int e = base + i * PTH + t;
        if (e < E) {
            int d = dst[e];
            int bk = d >> 8;
            int pos = lbase[bk] + atomicAdd(&lcnt[bk], 1);
            pairs[pos] = ((unsigned)src[e] << 8) | (unsigned)(d & 255);  // src<2^24
        }
    }
}

// one block per bucket: per-node hist -> scan -> rowp/norm -> col fill
__launch_bounds__(512)
__global__ void csr_build_kernel(const unsigned* __restrict__ pairs, const int* __restrict__ bbase,
                                 int* __restrict__ rowp, float* __restrict__ norm,
                                 int* __restrict__ col, int N) {
    __shared__ int lcnt[BN];
    __shared__ int lsc[BN];
    __shared__ int lcur[BN];
    int b = blockIdx.x;
    int t = threadIdx.x;
    int beg = bbase[b];
    int end = bbase[b + 1];
    if (t < BN) lcnt[t] = 0;
    __syncthreads();
    for (int i = beg + t; i < end; i += 512)
        atomicAdd(&lcnt[pairs[i] & (BN - 1)], 1);
    __syncthreads();
    int c = (t < BN) ? lcnt[t] : 0;
    if (t < BN) lsc[t] = c;
    __syncthreads();
    for (int off = 1; off < BN; off <<= 1) {
        int u = (t < BN && t >= off) ? lsc[t - off] : 0;
        __syncthreads();
        if (t < BN) lsc[t] += u;
        __syncthreads();
    }
    if (t < BN) {
        int ex = lsc[t] - c;  // exclusive local prefix
        lcur[t] = ex;
        int node = b * BN + t;
        if (node < N) {
            rowp[node] = beg + ex;
            norm[node] = rsqrtf(fmaxf((float)c, 1.0f));
        }
    }
    __syncthreads();
    for (int i = beg + t; i < end; i += 512) {
        unsigned p = pairs[i];
        int pos = atomicAdd(&lcur[p & (BN - 1)], 1);
        col[beg + pos] = (int)(p >> 8);
    }
}

// ---- dense pipeline -----------------------------------------------------

// xs = feat * norm[row], bf16 (halves gather traffic; folds src-norm weight)
__global__ void prescale_kernel(const float* __restrict__ feat, const float* __restrict__ norm,
                                short* __restrict__ xs, int Ntot) {
    int t = blockIdx.x * blockDim.x + threadIdx.x;
    if (t * 8 >= Ntot) return;
    float nm = norm[t >> 3];
    f32x4 a = *(const f32x4*)(feat + (size_t)t * 8);
    f32x4 b = *(const f32x4*)(feat + (size_t)t * 8 + 4);
    bf16x8 o;
    for (int j = 0; j < 4; ++j) {
        o[j] = f2bf(a[j] * nm);
        o[4 + j] = f2bf(b[j] * nm);
    }
    *(bf16x8*)(xs + (size_t)t * 8) = o;
}

// Row-sum gather, 4 edges/iteration: 16-lane group g handles edge eb+g,
// each lane loads 8B (4 bf16 dims). No bound check in the full-quad body;
// unroll 4 for 8 loads in flight. One butterfly per node.
// MODE 0: o1 = Tx1 = C1A*norm[n]*acc ; o2 = Tx1*norm[n]   (both bf16)
// MODE 1: o1 = acc (raw sum, bf16)
template <int MODE>
__launch_bounds__(256)
__global__ void gather_kernel(const short* __restrict__ xb, const float* __restrict__ norm,
                              const int* __restrict__ rowp, const int* __restrict__ col,
                              short* __restrict__ o1, short* __restrict__ o2, int N) {
    int n = blockIdx.x * 4 + (threadIdx.x >> 6);
    int lane = threadIdx.x & 63;
    if (n >= N) return;
    int g = lane >> 4;          // edge slot 0..3
    int dl = (lane & 15) << 2;  // dim base 0,4,..,60
    int beg = rowp[n];
    int end = rowp[n + 1];
    const short* rb = xb + dl;
    float a0 = 0.f, a1 = 0.f, a2 = 0.f, a3 = 0.f;
    int cnt = end - beg;
    int fullEnd = beg + (cnt & ~3);
    int eb = beg;
#pragma unroll 4
    for (; eb < fullEnd; eb += 4) {
        int s = col[eb + g];
        u32x2 v = *(const u32x2*)(rb + ((size_t)(unsigned)s << 6));
        a0 += __builtin_bit_cast(float, v[0] << 16);
        a1 += __builtin_bit_cast(float, v[0] & 0xffff0000u);
        a2 += __builtin_bit_cast(float, v[1] << 16);
        a3 += __builtin_bit_cast(float, v[1] & 0xffff0000u);
    }
    if (eb < end) {  // tail: masked groups
        int e = eb + g;
        u32x2 v = {0u, 0u};
        if (e < end) {
            int s = col[e];
            v = *(const u32x2*)(rb + ((size_t)(unsigned)s << 6));
        }
        a0 += __builtin_bit_cast(float, v[0] << 16);
        a1 += __builtin_bit_cast(float, v[0] & 0xffff0000u);
        a2 += __builtin_bit_cast(float, v[1] << 16);
        a3 += __builtin_bit_cast(float, v[1] & 0xffff0000u);
    }
    a0 += __shfl_xor(a0, 16); a0 += __shfl_xor(a0, 32);
    a1 += __shfl_xor(a1, 16); a1 += __shfl_xor(a1, 32);
    a2 += __shfl_xor(a2, 16); a2 += __shfl_xor(a2, 32);
    a3 += __shfl_xor(a3, 16); a3 += __shfl_xor(a3, 32);
    if (g == 0) {
        size_t o = (size_t)n * DD + dl;
        if (MODE == 0) {
            float nm = norm[n];
            float t0 = C1A * nm * a0, t1 = C1A * nm * a1;
            float t2 = C1A * nm * a2, t3 = C1A * nm * a3;
            bf16x4 r1 = {f2bf(t0), f2bf(t1), f2bf(t2), f2bf(t3)};
            *(bf16x4*)(o1 + o) = r1;
            bf16x4 r2 = {f2bf(t0 * nm), f2bf(t1 * nm), f2bf(t2 * nm), f2bf(t3 * nm)};
            *(bf16x4*)(o2 + o) = r2;
        } else {
            bf16x4 r = {f2bf(a0), f2bf(a1), f2bf(a2), f2bf(a3)};
            *(bf16x4*)(o1 + o) = r;
        }
    }
}

// out = x0@W0 + Tx1@W1 + Tx2@W2 + bias;  Tx2 = C2A*norm[n]*t2sum + C2B*Tx1 - x0
__launch_bounds__(256)
__global__ void out_kernel(const float* __restrict__ feat,
                           const short* __restrict__ t1b,
                           const short* __restrict__ t2s,
                           const float* __restrict__ norm,
                           const float* __restrict__ W,
                           const float* __restrict__ bias,
                           float* __restrict__ out, int N) {
    __shared__ __align__(16) short sW[3][64][72];
    for (int idx = threadIdx.x; idx < 3 * 64 * 64; idx += 256) {
        int m = idx >> 12;
        int r = idx & 4095;
        int k = r >> 6;
        int n = r & 63;
        sW[m][n][k] = f2bf(W[idx]);  // W flat = m*4096 + k*64 + n
    }
    __syncthreads();

    int wave = threadIdx.x >> 6;
    int lane = threadIdx.x & 63;
    int rowtile = blockIdx.x * 64 + wave * 16;
    if (rowtile >= N) return;
    int lrow = lane & 15;
    int lk = (lane >> 4) << 3;  // 0,8,16,24
    int row = rowtile + lrow;
    bool rv = row < N;
    float nrm = rv ? norm[row] : 0.0f;

    bf16x8 a[3][2];
    for (int s = 0; s < 2; ++s) {
        if (rv) {
            size_t base = (size_t)row * DD + s * 32 + lk;
            f32x4 fa = *(const f32x4*)(feat + base);
            f32x4 fb = *(const f32x4*)(feat + base + 4);
            bf16x8 t1v = *(const bf16x8*)(t1b + base);
            bf16x8 t2v = *(const bf16x8*)(t2s + base);
            a[1][s] = t1v;
            for (int j = 0; j < 8; ++j) {
                float xf = (j < 4) ? fa[j] : fb[j - 4];
                float T2 = C2A * nrm * bf2f(t2v[j]) - xf;
                if (C2B != 0.0f) T2 += C2B * bf2f(t1v[j]);
                a[0][s][j] = f2bf(xf);
                a[2][s][j] = f2bf(T2);
            }
        } else {
            for (int j = 0; j < 8; ++j) { a[0][s][j] = 0; a[1][s][j] = 0; a[2][s][j] = 0; }
        }
    }

    f32x4 acc[4];
    for (int ct = 0; ct < 4; ++ct) acc[ct] = (f32x4){0.f, 0.f, 0.f, 0.f};

    for (int m = 0; m < 3; ++m)
        for (int s = 0; s < 2; ++s)
            for (int ct = 0; ct < 4; ++ct) {
                bf16x8 bfr = *(const bf16x8*)&sW[m][ct * 16 + lrow][s * 32 + lk];
                acc[ct] = __builtin_amdgcn_mfma_f32_16x16x32_bf16(a[m][s], bfr, acc[ct], 0, 0, 0);
            }

    // C/D layout: col = lane&15, row = (lane>>4)*4 + reg  [verified m89/m91]
    int rbase = rowtile + ((lane >> 4) << 2);
    for (int ct = 0; ct < 4; ++ct) {
        int colo = ct * 16 + lrow;
        float bv = bias[colo];
        for (int r = 0; r < 4; ++r) {
            int ro = rbase + r;
            if (ro < N) out[(size_t)ro * DD + colo] = acc[ct][r] + bv;
        }
    }
}

extern "C" void kernel_launch(void* const* d_in, const int* in_sizes, int n_in,
                              void* d_out, int out_size, void* d_ws, size_t ws_size,
                              hipStream_t stream) {
    const float* feat = (const float*)d_in[0];
    const float* W    = (const float*)d_in[1];
    const float* bias = (const float*)d_in[2];
    const int* esrc   = (const int*)d_in[3];
    const int* edst   = (const int*)d_in[4];
    float* out = (float*)d_out;

    char* ws = (char*)d_ws;
    size_t off = 0;
    auto alloc = [&](size_t bytes) {
        void* p = ws + off;
        off = (off + bytes + 255) & ~(size_t)255;
        return p;
    };
    int*      rowp  = (int*)alloc(((size_t)NN + 1) * 4);
    float*    norm  = (float*)alloc((size_t)NN * 4);
    int*      bcnt  = (int*)alloc((size_t)NBK * 4);
    int*      bbase = (int*)alloc(((size_t)NBK + 1) * 4);
    int*      bcur  = (int*)alloc((size_t)NBK * 4);
    int*      col   = (int*)alloc((size_t)NE * 4);
    unsigned* pairs = (unsigned*)alloc((size_t)NE * 4);
    short*    xs    = (short*)alloc((size_t)NN * DD * 2);
    short*    t1b   = (short*)alloc((size_t)NN * DD * 2);
    short*    t1s   = (short*)alloc((size_t)NN * DD * 2);
    short*    t2s   = xs;  // alias: xs dead after gather<0>

    hipMemsetAsync(bcnt, 0, (size_t)NBK * 4, stream);

    bhist_kernel<<<ABL, PTH, 0, stream>>>(edst, bcnt, NE);
    bscan_kernel<<<1, 512, 0, stream>>>(bcnt, bbase, bcur, rowp);
    bfill_kernel<<<ABL, PTH, 0, stream>>>(esrc, edst, bcur, pairs, NE);
    csr_build_kernel<<<NBK, 512, 0, stream>>>(pairs, bbase, rowp, norm, col, NN);
    prescale_kernel<<<(NN * DD / 8 + 255) / 256, 256, 0, stream>>>(feat, norm, xs, NN * DD);
    gather_kernel<0><<<(NN + 3) / 4, 256, 0, stream>>>(xs, norm, rowp, col, t1b, t1s, NN);
    gather_kernel<1><<<(NN + 3) / 4, 256, 0, stream>>>(t1s, norm, rowp, col, t2s, nullptr, NN);
    out_kernel<<<(NN + 63) / 64, 256, 0, stream>>>(feat, t1b, t2s, norm, W, bias, out, NN);
}